// Round 17
// baseline (197.441 us; speedup 1.0000x reference)
//
#include <hip/hip_runtime.h>
#include <hip/hip_bf16.h>

typedef __bf16 bf16_t;
typedef __bf16 bf16x4 __attribute__((ext_vector_type(4)));
typedef __bf16 bf16x8 __attribute__((ext_vector_type(8)));
typedef float  f32x4  __attribute__((ext_vector_type(4)));

// ---------------------------------------------------------------- helpers
__device__ __forceinline__ void gload_lds16(const void* g, void* l)
{
    __builtin_amdgcn_global_load_lds((__attribute__((address_space(1))) void*)g,
                                     (__attribute__((address_space(3))) void*)l,
                                     16, 0, 0);
}

// ---------------------------------------------------------------- fused fp32 -> bf16 casts (x1|x2 -> xcat, W1, W2)
__global__ __launch_bounds__(256) void cast_all(const float* __restrict__ x1, const float* __restrict__ x2,
                                                const float* __restrict__ W1, const float* __restrict__ W2,
                                                bf16_t* __restrict__ xcatb, bf16_t* __restrict__ W1b,
                                                bf16_t* __restrict__ W2b)
{
    const size_t i  = ((size_t)blockIdx.x * 256 + threadIdx.x) * 4;
    const size_t M4 = 1ull << 22;              // 4M elements per region
    const size_t r  = i >> 22;
    const size_t off = i & (M4 - 1);
    const float* src; bf16_t* dst;
    if (r == 0)      { src = x1; dst = xcatb; }
    else if (r == 1) { src = x2; dst = xcatb + M4; }
    else if (r == 2) { src = W1; dst = W1b; }
    else             { src = W2; dst = W2b; }
    f32x4 v = *(const f32x4*)(src + off);
    bf16x4 o;
    o[0] = (bf16_t)v[0]; o[1] = (bf16_t)v[1]; o[2] = (bf16_t)v[2]; o[3] = (bf16_t)v[3];
    *(bf16x4*)(dst + off) = o;
}

// ---------------------------------------------------------------- counted-vmcnt GEMM v5: BK=64 phases, half the barriers
// 256x128 tile, grid 16x16 = 256 blocks, 8 waves (4m x 2n), per-wave 64x64, acc[4][4].
// Ring-3 slots of 48KB; each slot = TWO contiguous k32 sub-units with the R10-validated layout
// (A 256x32 = 16KB + B 128x32 = 8KB each; chunk c of row stored at (c+(row>>1))&3, inverse on src).
// Phase p (32 phases): { stage slot (p+1)%3 [6 gloads/thread] -> vmcnt(6) -> ONE barrier ->
//                        16 ds_read frags (sub-units 0,1) -> setprio + 32 MFMA }.
// Restage safety (gemm8d argument): slot (p+1)%3 last read at phase p-2; those reads lgkm-drained
// before MFMA(p-2), hence before every wave crossed BAR(p-1); stage(p) issues after BAR(p-1) ->
// >=1 full barrier between last read and restage. vmcnt(6): batch(p)=6 complete, batch(p+1)=6 in
// flight; vmcnt(0) only at p=31. MFMA k-order per output unchanged (k32 #0 then #1).
// mode 1: + col sum/sumsq partials. mode 2: + rn scaling (rn recomputed in-epilogue from rsq
// partials, fixed order -> bitwise deterministic), row argmax + LSE partials. mode 3: + row sumsq.
__global__ __launch_bounds__(512) void gemm8f(
    const bf16_t* __restrict__ A, const bf16_t* __restrict__ B,
    const float* __restrict__ bias, bf16_t* __restrict__ C,
    long long b_batch_stride, int mode,
    float* __restrict__ ps, float* __restrict__ ps2,
    float* __restrict__ rsq,
    unsigned long long* __restrict__ pkey, float* __restrict__ lseP)
{
    __shared__ __align__(16) char smem[147456];  // 3 slots x 48KB; epilogue scratch aliased
    bf16_t* ring = (bf16_t*)smem;
    const int tid  = threadIdx.x;
    const int lane = tid & 63;
    const int wave = tid >> 6;
    const int l15  = lane & 15;
    const int cg   = lane >> 4;
    const int wm   = (wave >> 1) * 64;            // 4 m-groups
    const int wn   = (wave & 1) * 64;             // 2 n-halves
    const int m0   = blockIdx.y * 256;
    const int n0   = blockIdx.x * 128;
    const int K = 2048, N = 2048;
    const bf16_t* Bb = B + (size_t)(m0 >> 11) * b_batch_stride;

    f32x4 acc[4][4] = {};

    auto STAGE_A = [&](int k0, bf16_t* dst) {     // one k32 A sub-unit: 2 gloads/thread
#pragma unroll
        for (int i = 0; i < 2; ++i) {
            const int ch  = wave * 128 + i * 64 + lane;        // dest 16B chunk, linear in lane
            const int row = ch >> 2;
            const int cs  = ((ch & 3) - ((row >> 1) & 3)) & 3; // inverse perm on source
            gload_lds16(A + (size_t)(m0 + row) * K + k0 + cs * 8, dst + ch * 8);
        }
    };
    auto STAGE_B = [&](int k0, bf16_t* dst) {     // one k32 B sub-unit: 1 gload/thread
        const int ch  = wave * 64 + lane;
        const int row = ch >> 2;
        const int cs  = ((ch & 3) - ((row >> 1) & 3)) & 3;
        gload_lds16(Bb + (size_t)(n0 + row) * K + k0 + cs * 8, dst + ch * 8);
    };
    auto STAGE_SLOT = [&](int k0, int s) {        // BK=64 slot = 2 sub-units; 6 gloads/thread
        bf16_t* base = ring + s * 24576;
        STAGE_A(k0,      base);
        STAGE_B(k0,      base + 8192);
        STAGE_A(k0 + 32, base + 12288);
        STAGE_B(k0 + 32, base + 20480);
    };
    auto FRAG = [&](const bf16_t* u, int row) -> bf16x8 {
        const int p = (cg + (row >> 1)) & 3;                   // stored position of chunk cg
        return *(const bf16x8*)&u[row * 32 + p * 8];
    };

    // prologue: stage slot 0 (phase 0's data)
    STAGE_SLOT(0, 0);

    for (int p = 0; p < 32; ++p) {
        bf16_t* base = ring + (p % 3) * 24576;
        if (p < 31) {
            STAGE_SLOT((p + 1) * 64, (p + 1) % 3);
            asm volatile("s_waitcnt vmcnt(6)" ::: "memory");   // batch(p) complete, batch(p+1) in flight
        } else {
            asm volatile("s_waitcnt vmcnt(0)" ::: "memory");   // drain final batch
        }
        __builtin_amdgcn_sched_barrier(0);
        __builtin_amdgcn_s_barrier();                          // all waves' slot-p stages visible
        bf16x8 af0[4], bf0[4], af1[4], bf1[4];
#pragma unroll
        for (int f = 0; f < 4; ++f) af0[f] = FRAG(base,         wm + f * 16 + l15);
#pragma unroll
        for (int f = 0; f < 4; ++f) bf0[f] = FRAG(base + 8192,  wn + f * 16 + l15);
#pragma unroll
        for (int f = 0; f < 4; ++f) af1[f] = FRAG(base + 12288, wm + f * 16 + l15);
#pragma unroll
        for (int f = 0; f < 4; ++f) bf1[f] = FRAG(base + 20480, wn + f * 16 + l15);
        __builtin_amdgcn_s_setprio(1);
#pragma unroll
        for (int fm = 0; fm < 4; ++fm)
#pragma unroll
            for (int fn = 0; fn < 4; ++fn)
                acc[fm][fn] = __builtin_amdgcn_mfma_f32_16x16x32_bf16(af0[fm], bf0[fn], acc[fm][fn], 0, 0, 0);
#pragma unroll
        for (int fm = 0; fm < 4; ++fm)
#pragma unroll
            for (int fn = 0; fn < 4; ++fn)
                acc[fm][fn] = __builtin_amdgcn_mfma_f32_16x16x32_bf16(af1[fm], bf1[fn], acc[fm][fn], 0, 0, 0);
        __builtin_amdgcn_s_setprio(0);
        // no trailing barrier: MFMA(p) overlaps phase p+1's stage/vmcnt
    }
    __syncthreads();   // ring dead; reuse as epilogue scratch

    // ---- mode2: recompute rn in-epilogue (norm_final folded): rn[r] = 1/max(sqrt(sum16 rsq), 1e-12),
    //      fixed nb order -> bitwise deterministic; then acc[m][n] *= rn_m * rn_n
    if (mode == 2) {
        const int rnb = (m0 >> 11) * 2048;   // branch base for the col side
        auto RN = [&](int r) -> float {
            float s = 0.f;
#pragma unroll
            for (int nb = 0; nb < 16; ++nb) s += rsq[(size_t)nb * 4096 + r];
            return 1.0f / fmaxf(sqrtf(s), 1e-12f);
        };
#pragma unroll
        for (int fm = 0; fm < 4; ++fm) {
            const int mb = m0 + wm + fm * 16 + cg * 4;
            f32x4 rm;
#pragma unroll
            for (int r = 0; r < 4; ++r) rm[r] = RN(mb + r);
#pragma unroll
            for (int fn = 0; fn < 4; ++fn) {
                const float rc = RN(rnb + n0 + wn + fn * 16 + l15);
#pragma unroll
                for (int r = 0; r < 4; ++r)
                    acc[fm][fn][r] *= rm[r] * rc;
            }
        }
    }

    // ---- C write (+bias), bf16. C/D layout: col = lane&15, row = (lane>>4)*4 + reg
#pragma unroll
    for (int fm = 0; fm < 4; ++fm) {
        const int rb = m0 + wm + fm * 16 + cg * 4;
#pragma unroll
        for (int fn = 0; fn < 4; ++fn) {
            const int colg = n0 + wn + fn * 16 + l15;
            const float bv = bias ? bias[colg] : 0.0f;
#pragma unroll
            for (int r = 0; r < 4; ++r)
                C[(size_t)(rb + r) * N + colg] = (bf16_t)(acc[fm][fn][r] + bv);
        }
    }

    if (mode == 1) {
        // col sum/sumsq over this block's 256 rows. Col j: waves {p,p+2,p+4,p+6}, p=j>>6.
        float* cs2 = (float*)smem;            // [8][64]
        float* cq2 = cs2 + 512;               // [8][64]
#pragma unroll
        for (int fn = 0; fn < 4; ++fn) {
            const int cl = fn * 16 + l15;                  // 0..63 within wave's cols
            const float bv = bias[n0 + wn + cl];
            float s = 0.f, q = 0.f;
#pragma unroll
            for (int fm = 0; fm < 4; ++fm)
#pragma unroll
                for (int r = 0; r < 4; ++r) {
                    const float v = acc[fm][fn][r] + bv;
                    s += v; q += v * v;
                }
            s += __shfl_xor(s, 16); q += __shfl_xor(q, 16);
            s += __shfl_xor(s, 32); q += __shfl_xor(q, 32);
            if (lane < 16) { cs2[wave * 64 + cl] = s; cq2[wave * 64 + cl] = q; }
        }
        __syncthreads();
        if (tid < 128) {
            const int p = tid >> 6, cl = tid & 63;
            ps [(size_t)blockIdx.y * 2048 + n0 + tid] =
                cs2[p * 64 + cl] + cs2[(p + 2) * 64 + cl] + cs2[(p + 4) * 64 + cl] + cs2[(p + 6) * 64 + cl];
            ps2[(size_t)blockIdx.y * 2048 + n0 + tid] =
                cq2[p * 64 + cl] + cq2[(p + 2) * 64 + cl] + cq2[(p + 4) * 64 + cl] + cq2[(p + 6) * 64 + cl];
        }
    } else if (mode == 3) {
        // row sumsq of (acc+bias) over this block's 128 cols. Row j: waves {2mg,2mg+1}, mg=j>>6.
        float* rq2 = (float*)smem;            // [8][64]
#pragma unroll
        for (int fm = 0; fm < 4; ++fm)
#pragma unroll
            for (int r = 0; r < 4; ++r) {
                float q = 0.f;
#pragma unroll
                for (int fn = 0; fn < 4; ++fn) {
                    const float v = acc[fm][fn][r] + bias[n0 + wn + fn * 16 + l15];
                    q += v * v;
                }
                q += __shfl_xor(q, 1); q += __shfl_xor(q, 2);
                q += __shfl_xor(q, 4); q += __shfl_xor(q, 8);
                if (l15 == 0) rq2[wave * 64 + fm * 16 + cg * 4 + r] = q;
            }
        __syncthreads();
        if (tid < 256) {
            const int mg = tid >> 6, rl = tid & 63;
            rsq[(size_t)blockIdx.x * 4096 + m0 + tid] =
                rq2[2 * mg * 64 + rl] + rq2[(2 * mg + 1) * 64 + rl];
        }
    } else if (mode == 2) {
        // row argmax + LSE over this block's 128 cols (scaled acc), self excluded.
        float* ls2 = (float*)smem;                                    // [8][64]
        unsigned long long* kv2 = (unsigned long long*)(smem + 4096); // [8][64]
#pragma unroll
        for (int fm = 0; fm < 4; ++fm)
#pragma unroll
            for (int r = 0; r < 4; ++r) {
                const int rl   = fm * 16 + cg * 4 + r;
                const int self = (m0 + wm + rl) & 2047;
                float best = -1.0e38f; int bi = 0x7fffffff; float se = 0.f;
#pragma unroll
                for (int fn = 0; fn < 4; ++fn) {
                    const int cgl = n0 + wn + fn * 16 + l15;
                    const float v = acc[fm][fn][r];
                    if (cgl != self) {
                        se += __expf(10.0f * v);
                        if (v > best) { best = v; bi = cgl; }
                    }
                }
#pragma unroll
                for (int st2 = 1; st2 <= 8; st2 <<= 1) {
                    const float ov = __shfl_xor(best, st2);
                    const int   oi = __shfl_xor(bi, st2);
                    if (ov > best || (ov == best && oi < bi)) { best = ov; bi = oi; }
                    se += __shfl_xor(se, st2);
                }
                if (l15 == 0) {
                    unsigned u = __float_as_uint(best);
                    u = (u & 0x80000000u) ? ~u : (u | 0x80000000u);
                    kv2[wave * 64 + rl] = ((unsigned long long)u << 32) | (unsigned)(~bi);
                    ls2[wave * 64 + rl] = se;
                }
            }
        __syncthreads();
        if (tid < 256) {
            const int mg = tid >> 6, rl = tid & 63;
            const unsigned long long a = kv2[2 * mg * 64 + rl], b = kv2[(2 * mg + 1) * 64 + rl];
            pkey[(size_t)blockIdx.x * 4096 + m0 + tid] = a > b ? a : b;
            lseP[(size_t)blockIdx.x * 4096 + m0 + tid] =
                ls2[2 * mg * 64 + rl] + ls2[(2 * mg + 1) * 64 + rl];
        }
    }
}

// ---------------------------------------------------------------- BN finalize from 8 per-mblock partials (256-row blocks)
__global__ __launch_bounds__(256) void bn_final2(const float* __restrict__ ps, const float* __restrict__ ps2,
                                                 float* __restrict__ mu, float* __restrict__ rinv)
{
    const int c = blockIdx.x * 256 + threadIdx.x;  // 0..4095
    const int b = c >> 11, col = c & 2047;
    float s = 0.f, s2 = 0.f;
    for (int i = 0; i < 8; ++i) {
        s  += ps [(size_t)(b * 8 + i) * 2048 + col];
        s2 += ps2[(size_t)(b * 8 + i) * 2048 + col];
    }
    const float m = s * (1.0f / 2048.0f);
    const float v = s2 * (1.0f / 2048.0f) - m * m;   // biased var
    mu[c]   = m;
    rinv[c] = rsqrtf(v + 1e-5f);
}

// ---------------------------------------------------------------- BN apply + ReLU on bf16 h -> bf16 hn
__global__ __launch_bounds__(256) void bn_apply(const bf16_t* __restrict__ h, const float* __restrict__ mu,
                                                const float* __restrict__ rinv, const float* __restrict__ gamma,
                                                const float* __restrict__ beta, bf16_t* __restrict__ out)
{
    const size_t base = ((size_t)blockIdx.x * 256 + threadIdx.x) * 8;
    const int col = (int)(base & 2047);
    const int br  = (int)(base >> 22);
    bf16x8 v = *(const bf16x8*)(h + base);
    bf16x8 o;
#pragma unroll
    for (int j = 0; j < 8; ++j) {
        const int c = col + j;
        const float f = (float)v[j];
        const float t = (f - mu[br * 2048 + c]) * rinv[br * 2048 + c] * gamma[c] + beta[c];
        o[j] = (bf16_t)fmaxf(t, 0.0f);
    }
    *(bf16x8*)(out + base) = o;
}

// ---------------------------------------------------------------- CC (argmax-combine folded), early-exit, 1 block/branch
__global__ __launch_bounds__(1024) void cc_labels(const unsigned long long* __restrict__ pkey,
                                                  int* __restrict__ labg)
{
    __shared__ int A_[2048];
    __shared__ int Bn[2048];
    __shared__ int Y_[2048];
    __shared__ int chg;
    const int br = blockIdx.x;
    const int t = threadIdx.x;
    if (t == 0) chg = 0;
    for (int i = t; i < 2048; i += 1024) {
        const int row = br * 2048 + i;
        unsigned long long k = 0ull;
        for (int nb = 0; nb < 16; ++nb) {
            const unsigned long long v = pkey[(size_t)nb * 4096 + row];
            k = (v > k) ? v : k;
        }
        Y_[i] = (int)~((unsigned)(k & 0xFFFFFFFFull));
        A_[i] = i;
    }
    __syncthreads();
    for (int it = 0; it < 32; ++it) {
        for (int i = t; i < 2048; i += 1024) Bn[i] = min(A_[i], A_[Y_[i]]);
        __syncthreads();
        for (int i = t; i < 2048; i += 1024) atomicMin(&Bn[Y_[i]], A_[i]);
        __syncthreads();
        int ch = 0;
        for (int i = t; i < 2048; i += 1024) {
            const int b = Bn[i];
            const int nv = min(b, Bn[b]);
            if (nv != A_[i]) { ch = 1; A_[i] = nv; }
        }
        if (ch) atomicOr(&chg, 1);
        __syncthreads();
        const int c = chg;
        __syncthreads();
        if (t == 0) chg = 0;
        if (!c) break;
    }
    for (int i = t; i < 2048; i += 1024) labg[br * 2048 + i] = A_[i];
}

// ---------------------------------------------------------------- per-row term from bf16 sim + exact LSE partials
__global__ __launch_bounds__(256) void loss_rows(const bf16_t* __restrict__ simb, const int* __restrict__ labels,
                                                 const float* __restrict__ lseP, float* __restrict__ terms)
{
    const int row = blockIdx.x;
    const int br  = row >> 11;
    const int* lab = labels + ((1 - br) << 11);
    const int self = row & 2047;
    const int li = lab[self];
    const int t = threadIdx.x;
    const bf16x8 v8 = *(const bf16x8*)(simb + (size_t)row * 2048 + t * 8);
    float psum = 0.f; int pc = 0;
#pragma unroll
    for (int j = 0; j < 8; ++j) {
        const int c = t * 8 + j;
        if (c == self) continue;
        if (lab[c] == li) { psum += 10.0f * (float)v8[j]; pc++; }
    }
    __shared__ float PS[256]; __shared__ int PC[256];
    PS[t] = psum; PC[t] = pc;
    __syncthreads();
    for (int off = 128; off; off >>= 1) {
        if (t < off) { PS[t] += PS[t + off]; PC[t] += PC[t + off]; }
        __syncthreads();
    }
    if (t == 0) {
        float se = 0.f;
        for (int nb = 0; nb < 16; ++nb) se += lseP[(size_t)nb * 4096 + row];
        terms[row] = logf(se) - PS[0] / (float)PC[0];
    }
}

// ---------------------------------------------------------------- final deterministic reduce
__global__ __launch_bounds__(1024) void final_reduce(const float* __restrict__ terms, float* __restrict__ out)
{
    const int t = threadIdx.x;
    float s = terms[t] + terms[t + 1024] + terms[t + 2048] + terms[t + 3072];
    __shared__ float S[1024];
    S[t] = s;
    __syncthreads();
    for (int off = 512; off; off >>= 1) { if (t < off) S[t] += S[t + off]; __syncthreads(); }
    if (t == 0) out[0] = S[0] * (1.0f / 4096.0f);
}

// ---------------------------------------------------------------- launch
extern "C" void kernel_launch(void* const* d_in, const int* in_sizes, int n_in,
                              void* d_out, int out_size, void* d_ws, size_t ws_size,
                              hipStream_t stream)
{
    const float* x1    = (const float*)d_in[0];
    const float* x2    = (const float*)d_in[1];
    const float* W1    = (const float*)d_in[2];
    const float* b1    = (const float*)d_in[3];
    const float* gamma = (const float*)d_in[4];
    const float* beta  = (const float*)d_in[5];
    const float* W2    = (const float*)d_in[6];
    const float* b2    = (const float*)d_in[7];

    char* ws = (char*)d_ws;
    const size_t MB = 1024ull * 1024ull;
    const size_t NN = 2048ull * 2048ull;
    bf16_t* W1b    = (bf16_t*)(ws + 0);
    bf16_t* W2b    = (bf16_t*)(ws + 8 * MB);
    bf16_t* xcatb  = (bf16_t*)(ws + 16 * MB);
    bf16_t* hnb    = (bf16_t*)(ws + 16 * MB);
    bf16_t* hb16   = (bf16_t*)(ws + 32 * MB);
    bf16_t* ob16   = (bf16_t*)(ws + 64 * MB);
    bf16_t* simb   = (bf16_t*)(ws + 0);
    float*  psA    = (float*)(ws + 80 * MB);               // [8][2048] col sums
    float*  psB    = psA + 32 * 2048;                       // [8][2048] col sumsq
    float*  rsq    = psB + 32 * 2048;                       // [16][4096] row sumsq
    float*  mu     = rsq + 16 * 4096;                       // [2][2048]
    float*  rinv   = mu + 4096;
    float*  lseP   = rinv + 4096;                           // [16][4096]
    unsigned long long* pkey = (unsigned long long*)(lseP + 16 * 4096);  // [16][4096]
    int*    labels = (int*)(pkey + 16 * 4096);
    float*  terms  = (float*)(labels + 4096);

    // fused casts
    cast_all<<<16384, 256, 0, stream>>>(x1, x2, W1, W2, xcatb, W1b, W2b);

    // h = xcat @ W1^T + b1 -> bf16, fused BN-stat partials
    gemm8f<<<dim3(16, 16), 512, 0, stream>>>(xcatb, W1b, b1, hb16, 0, 1,
                                             psA, psB, nullptr, nullptr, nullptr);
    bn_final2<<<16, 256, 0, stream>>>(psA, psB, mu, rinv);
    bn_apply<<<4096, 256, 0, stream>>>(hb16, mu, rinv, gamma, beta, hnb);

    // o = hn @ W2^T + b2 -> bf16, fused row-sumsq partials
    gemm8f<<<dim3(16, 16), 512, 0, stream>>>(hnb, W2b, b2, ob16, 0, 3,
                                             nullptr, nullptr, rsq, nullptr, nullptr);

    // sim = [o1@o1^T ; o2@o2^T] * rn_m*rn_n -> bf16 (rn recomputed in-epilogue from rsq),
    // fused row-argmax + row-LSE partials
    gemm8f<<<dim3(16, 16), 512, 0, stream>>>(ob16, ob16, nullptr, simb, (long long)NN, 2,
                                             nullptr, nullptr, rsq, pkey, lseP);

    // CC (argmax folded, early-exit) -> loss
    cc_labels<<<2, 1024, 0, stream>>>(pkey, labels);
    loss_rows<<<4096, 256, 0, stream>>>(simb, labels, lseP, terms);
    final_reduce<<<1, 1024, 0, stream>>>(terms, (float*)d_out);
}

// Round 18
// 193.437 us; speedup vs baseline: 1.0207x; 1.0207x over previous
//
#include <hip/hip_runtime.h>
#include <hip/hip_bf16.h>

typedef __bf16 bf16_t;
typedef __bf16 bf16x4 __attribute__((ext_vector_type(4)));
typedef __bf16 bf16x8 __attribute__((ext_vector_type(8)));
typedef float  f32x4  __attribute__((ext_vector_type(4)));

// ---------------------------------------------------------------- helpers
__device__ __forceinline__ void gload_lds16(const void* g, void* l)
{
    __builtin_amdgcn_global_load_lds((__attribute__((address_space(1))) void*)g,
                                     (__attribute__((address_space(3))) void*)l,
                                     16, 0, 0);
}

// ---------------------------------------------------------------- fused fp32 -> bf16 casts (x1|x2 -> xcat, W1, W2)
__global__ __launch_bounds__(256) void cast_all(const float* __restrict__ x1, const float* __restrict__ x2,
                                                const float* __restrict__ W1, const float* __restrict__ W2,
                                                bf16_t* __restrict__ xcatb, bf16_t* __restrict__ W1b,
                                                bf16_t* __restrict__ W2b)
{
    const size_t i  = ((size_t)blockIdx.x * 256 + threadIdx.x) * 4;
    const size_t M4 = 1ull << 22;              // 4M elements per region
    const size_t r  = i >> 22;
    const size_t off = i & (M4 - 1);
    const float* src; bf16_t* dst;
    if (r == 0)      { src = x1; dst = xcatb; }
    else if (r == 1) { src = x2; dst = xcatb + M4; }
    else if (r == 2) { src = W1; dst = W1b; }
    else             { src = W2; dst = W2b; }
    f32x4 v = *(const f32x4*)(src + off);
    bf16x4 o;
    o[0] = (bf16_t)v[0]; o[1] = (bf16_t)v[1]; o[2] = (bf16_t)v[2]; o[3] = (bf16_t)v[3];
    *(bf16x4*)(dst + off) = o;
}

// ---------------------------------------------------------------- counted-vmcnt GEMM v5: BK=64 phases, half the barriers
// 256x128 tile, grid 16x16 = 256 blocks, 8 waves (4m x 2n), per-wave 64x64, acc[4][4].
// Ring-3 slots of 48KB; each slot = TWO contiguous k32 sub-units with the R10-validated layout
// (A 256x32 = 16KB + B 128x32 = 8KB each; chunk c of row stored at (c+(row>>1))&3, inverse on src).
// Phase p (32 phases): { stage slot (p+1)%3 [6 gloads/thread] -> vmcnt(6) -> ONE barrier ->
//                        16 ds_read frags (sub-units 0,1) -> setprio + 32 MFMA }.
// Barrier count halves vs v3 (32 vs 64). Restage safety (gemm8d argument verbatim): slot (p+1)%3
// last read at phase p-2; those reads lgkm-drained before MFMA(p-2), hence before every wave
// crossed BAR(p-1); stage(p) issues after BAR(p-1) -> >=1 full barrier between last read and
// restage. vmcnt(6): batch(p)=6 complete, batch(p+1)=6 in flight; vmcnt(0) only at p=31.
// MFMA k-order per output unchanged (k32 #0 then #1).
// mode 1: + col sum/sumsq partials. mode 2: + rn scaling, row argmax + LSE partials. mode 3: + row sumsq.
__global__ __launch_bounds__(512) void gemm8f(
    const bf16_t* __restrict__ A, const bf16_t* __restrict__ B,
    const float* __restrict__ bias, bf16_t* __restrict__ C,
    long long b_batch_stride, int mode,
    float* __restrict__ ps, float* __restrict__ ps2,
    float* __restrict__ rsq, const float* __restrict__ rnv,
    unsigned long long* __restrict__ pkey, float* __restrict__ lseP)
{
    __shared__ __align__(16) char smem[147456];  // 3 slots x 48KB; epilogue scratch aliased
    bf16_t* ring = (bf16_t*)smem;
    const int tid  = threadIdx.x;
    const int lane = tid & 63;
    const int wave = tid >> 6;
    const int l15  = lane & 15;
    const int cg   = lane >> 4;
    const int wm   = (wave >> 1) * 64;            // 4 m-groups
    const int wn   = (wave & 1) * 64;             // 2 n-halves
    const int m0   = blockIdx.y * 256;
    const int n0   = blockIdx.x * 128;
    const int K = 2048, N = 2048;
    const bf16_t* Bb = B + (size_t)(m0 >> 11) * b_batch_stride;

    f32x4 acc[4][4] = {};

    auto STAGE_A = [&](int k0, bf16_t* dst) {     // one k32 A sub-unit: 2 gloads/thread
#pragma unroll
        for (int i = 0; i < 2; ++i) {
            const int ch  = wave * 128 + i * 64 + lane;        // dest 16B chunk, linear in lane
            const int row = ch >> 2;
            const int cs  = ((ch & 3) - ((row >> 1) & 3)) & 3; // inverse perm on source
            gload_lds16(A + (size_t)(m0 + row) * K + k0 + cs * 8, dst + ch * 8);
        }
    };
    auto STAGE_B = [&](int k0, bf16_t* dst) {     // one k32 B sub-unit: 1 gload/thread
        const int ch  = wave * 64 + lane;
        const int row = ch >> 2;
        const int cs  = ((ch & 3) - ((row >> 1) & 3)) & 3;
        gload_lds16(Bb + (size_t)(n0 + row) * K + k0 + cs * 8, dst + ch * 8);
    };
    auto STAGE_SLOT = [&](int k0, int s) {        // BK=64 slot = 2 sub-units; 6 gloads/thread
        bf16_t* base = ring + s * 24576;
        STAGE_A(k0,      base);
        STAGE_B(k0,      base + 8192);
        STAGE_A(k0 + 32, base + 12288);
        STAGE_B(k0 + 32, base + 20480);
    };
    auto FRAG = [&](const bf16_t* u, int row) -> bf16x8 {
        const int p = (cg + (row >> 1)) & 3;                   // stored position of chunk cg
        return *(const bf16x8*)&u[row * 32 + p * 8];
    };

    // prologue: stage slot 0 (phase 0's data)
    STAGE_SLOT(0, 0);

    for (int p = 0; p < 32; ++p) {
        bf16_t* base = ring + (p % 3) * 24576;
        if (p < 31) {
            STAGE_SLOT((p + 1) * 64, (p + 1) % 3);
            asm volatile("s_waitcnt vmcnt(6)" ::: "memory");   // batch(p) complete, batch(p+1) in flight
        } else {
            asm volatile("s_waitcnt vmcnt(0)" ::: "memory");   // drain final batch
        }
        __builtin_amdgcn_sched_barrier(0);
        __builtin_amdgcn_s_barrier();                          // all waves' slot-p stages visible
        bf16x8 af0[4], bf0[4], af1[4], bf1[4];
#pragma unroll
        for (int f = 0; f < 4; ++f) af0[f] = FRAG(base,         wm + f * 16 + l15);
#pragma unroll
        for (int f = 0; f < 4; ++f) bf0[f] = FRAG(base + 8192,  wn + f * 16 + l15);
#pragma unroll
        for (int f = 0; f < 4; ++f) af1[f] = FRAG(base + 12288, wm + f * 16 + l15);
#pragma unroll
        for (int f = 0; f < 4; ++f) bf1[f] = FRAG(base + 20480, wn + f * 16 + l15);
        __builtin_amdgcn_s_setprio(1);
#pragma unroll
        for (int fm = 0; fm < 4; ++fm)
#pragma unroll
            for (int fn = 0; fn < 4; ++fn)
                acc[fm][fn] = __builtin_amdgcn_mfma_f32_16x16x32_bf16(af0[fm], bf0[fn], acc[fm][fn], 0, 0, 0);
#pragma unroll
        for (int fm = 0; fm < 4; ++fm)
#pragma unroll
            for (int fn = 0; fn < 4; ++fn)
                acc[fm][fn] = __builtin_amdgcn_mfma_f32_16x16x32_bf16(af1[fm], bf1[fn], acc[fm][fn], 0, 0, 0);
        __builtin_amdgcn_s_setprio(0);
        // no trailing barrier: MFMA(p) overlaps phase p+1's stage/vmcnt
    }
    __syncthreads();   // ring dead; reuse as epilogue scratch

    // ---- mode2: fold row-normalization: acc[m][n] *= rn[m]*rn[n]
    if (mode == 2) {
        const int rnb = (m0 >> 11) * 2048;
#pragma unroll
        for (int fm = 0; fm < 4; ++fm) {
            const int mb = m0 + wm + fm * 16 + cg * 4;
            const f32x4 rm = *(const f32x4*)&rnv[mb];
#pragma unroll
            for (int fn = 0; fn < 4; ++fn) {
                const float rc = rnv[rnb + n0 + wn + fn * 16 + l15];
#pragma unroll
                for (int r = 0; r < 4; ++r)
                    acc[fm][fn][r] *= rm[r] * rc;
            }
        }
    }

    // ---- C write (+bias), bf16. C/D layout: col = lane&15, row = (lane>>4)*4 + reg
#pragma unroll
    for (int fm = 0; fm < 4; ++fm) {
        const int rb = m0 + wm + fm * 16 + cg * 4;
#pragma unroll
        for (int fn = 0; fn < 4; ++fn) {
            const int colg = n0 + wn + fn * 16 + l15;
            const float bv = bias ? bias[colg] : 0.0f;
#pragma unroll
            for (int r = 0; r < 4; ++r)
                C[(size_t)(rb + r) * N + colg] = (bf16_t)(acc[fm][fn][r] + bv);
        }
    }

    if (mode == 1) {
        // col sum/sumsq over this block's 256 rows. Col j: waves {p,p+2,p+4,p+6}, p=j>>6.
        float* cs2 = (float*)smem;            // [8][64]
        float* cq2 = cs2 + 512;               // [8][64]
#pragma unroll
        for (int fn = 0; fn < 4; ++fn) {
            const int cl = fn * 16 + l15;                  // 0..63 within wave's cols
            const float bv = bias[n0 + wn + cl];
            float s = 0.f, q = 0.f;
#pragma unroll
            for (int fm = 0; fm < 4; ++fm)
#pragma unroll
                for (int r = 0; r < 4; ++r) {
                    const float v = acc[fm][fn][r] + bv;
                    s += v; q += v * v;
                }
            s += __shfl_xor(s, 16); q += __shfl_xor(q, 16);
            s += __shfl_xor(s, 32); q += __shfl_xor(q, 32);
            if (lane < 16) { cs2[wave * 64 + cl] = s; cq2[wave * 64 + cl] = q; }
        }
        __syncthreads();
        if (tid < 128) {
            const int p = tid >> 6, cl = tid & 63;
            ps [(size_t)blockIdx.y * 2048 + n0 + tid] =
                cs2[p * 64 + cl] + cs2[(p + 2) * 64 + cl] + cs2[(p + 4) * 64 + cl] + cs2[(p + 6) * 64 + cl];
            ps2[(size_t)blockIdx.y * 2048 + n0 + tid] =
                cq2[p * 64 + cl] + cq2[(p + 2) * 64 + cl] + cq2[(p + 4) * 64 + cl] + cq2[(p + 6) * 64 + cl];
        }
    } else if (mode == 3) {
        // row sumsq of (acc+bias) over this block's 128 cols. Row j: waves {2mg,2mg+1}, mg=j>>6.
        float* rq2 = (float*)smem;            // [8][64]
#pragma unroll
        for (int fm = 0; fm < 4; ++fm)
#pragma unroll
            for (int r = 0; r < 4; ++r) {
                float q = 0.f;
#pragma unroll
                for (int fn = 0; fn < 4; ++fn) {
                    const float v = acc[fm][fn][r] + bias[n0 + wn + fn * 16 + l15];
                    q += v * v;
                }
                q += __shfl_xor(q, 1); q += __shfl_xor(q, 2);
                q += __shfl_xor(q, 4); q += __shfl_xor(q, 8);
                if (l15 == 0) rq2[wave * 64 + fm * 16 + cg * 4 + r] = q;
            }
        __syncthreads();
        if (tid < 256) {
            const int mg = tid >> 6, rl = tid & 63;
            rsq[(size_t)blockIdx.x * 4096 + m0 + tid] =
                rq2[2 * mg * 64 + rl] + rq2[(2 * mg + 1) * 64 + rl];
        }
    } else if (mode == 2) {
        // row argmax + LSE over this block's 128 cols (scaled acc), self excluded.
        float* ls2 = (float*)smem;                                    // [8][64]
        unsigned long long* kv2 = (unsigned long long*)(smem + 4096); // [8][64]
#pragma unroll
        for (int fm = 0; fm < 4; ++fm)
#pragma unroll
            for (int r = 0; r < 4; ++r) {
                const int rl   = fm * 16 + cg * 4 + r;
                const int self = (m0 + wm + rl) & 2047;
                float best = -1.0e38f; int bi = 0x7fffffff; float se = 0.f;
#pragma unroll
                for (int fn = 0; fn < 4; ++fn) {
                    const int cgl = n0 + wn + fn * 16 + l15;
                    const float v = acc[fm][fn][r];
                    if (cgl != self) {
                        se += expf(10.0f * v);
                        if (v > best) { best = v; bi = cgl; }
                    }
                }
#pragma unroll
                for (int st2 = 1; st2 <= 8; st2 <<= 1) {
                    const float ov = __shfl_xor(best, st2);
                    const int   oi = __shfl_xor(bi, st2);
                    if (ov > best || (ov == best && oi < bi)) { best = ov; bi = oi; }
                    se += __shfl_xor(se, st2);
                }
                if (l15 == 0) {
                    unsigned u = __float_as_uint(best);
                    u = (u & 0x80000000u) ? ~u : (u | 0x80000000u);
                    kv2[wave * 64 + rl] = ((unsigned long long)u << 32) | (unsigned)(~bi);
                    ls2[wave * 64 + rl] = se;
                }
            }
        __syncthreads();
        if (tid < 256) {
            const int mg = tid >> 6, rl = tid & 63;
            const unsigned long long a = kv2[2 * mg * 64 + rl], b = kv2[(2 * mg + 1) * 64 + rl];
            pkey[(size_t)blockIdx.x * 4096 + m0 + tid] = a > b ? a : b;
            lseP[(size_t)blockIdx.x * 4096 + m0 + tid] =
                ls2[2 * mg * 64 + rl] + ls2[(2 * mg + 1) * 64 + rl];
        }
    }
}

// ---------------------------------------------------------------- BN finalize from 8 per-mblock partials (256-row blocks)
__global__ __launch_bounds__(256) void bn_final2(const float* __restrict__ ps, const float* __restrict__ ps2,
                                                 float* __restrict__ mu, float* __restrict__ rinv)
{
    const int c = blockIdx.x * 256 + threadIdx.x;  // 0..4095
    const int b = c >> 11, col = c & 2047;
    float s = 0.f, s2 = 0.f;
    for (int i = 0; i < 8; ++i) {
        s  += ps [(size_t)(b * 8 + i) * 2048 + col];
        s2 += ps2[(size_t)(b * 8 + i) * 2048 + col];
    }
    const float m = s * (1.0f / 2048.0f);
    const float v = s2 * (1.0f / 2048.0f) - m * m;   // biased var
    mu[c]   = m;
    rinv[c] = rsqrtf(v + 1e-5f);
}

// ---------------------------------------------------------------- BN apply + ReLU on bf16 h -> bf16 hn
__global__ __launch_bounds__(256) void bn_apply(const bf16_t* __restrict__ h, const float* __restrict__ mu,
                                                const float* __restrict__ rinv, const float* __restrict__ gamma,
                                                const float* __restrict__ beta, bf16_t* __restrict__ out)
{
    const size_t base = ((size_t)blockIdx.x * 256 + threadIdx.x) * 8;
    const int col = (int)(base & 2047);
    const int br  = (int)(base >> 22);
    bf16x8 v = *(const bf16x8*)(h + base);
    bf16x8 o;
#pragma unroll
    for (int j = 0; j < 8; ++j) {
        const int c = col + j;
        const float f = (float)v[j];
        const float t = (f - mu[br * 2048 + c]) * rinv[br * 2048 + c] * gamma[c] + beta[c];
        o[j] = (bf16_t)fmaxf(t, 0.0f);
    }
    *(bf16x8*)(out + base) = o;
}

// ---------------------------------------------------------------- rn[r] = 1/max(||o_r||, 1e-12) from 16 partials
__global__ __launch_bounds__(256) void norm_final(const float* __restrict__ rsq, float* __restrict__ rn)
{
    const int r = blockIdx.x * 256 + threadIdx.x;
    float s = 0.f;
    for (int nb = 0; nb < 16; ++nb) s += rsq[(size_t)nb * 4096 + r];
    rn[r] = 1.0f / fmaxf(sqrtf(s), 1e-12f);
}

// ---------------------------------------------------------------- CC (argmax-combine folded), early-exit, 1 block/branch
__global__ __launch_bounds__(1024) void cc_labels(const unsigned long long* __restrict__ pkey,
                                                  int* __restrict__ labg)
{
    __shared__ int A_[2048];
    __shared__ int Bn[2048];
    __shared__ int Y_[2048];
    __shared__ int chg;
    const int br = blockIdx.x;
    const int t = threadIdx.x;
    if (t == 0) chg = 0;
    for (int i = t; i < 2048; i += 1024) {
        const int row = br * 2048 + i;
        unsigned long long k = 0ull;
        for (int nb = 0; nb < 16; ++nb) {
            const unsigned long long v = pkey[(size_t)nb * 4096 + row];
            k = (v > k) ? v : k;
        }
        Y_[i] = (int)~((unsigned)(k & 0xFFFFFFFFull));
        A_[i] = i;
    }
    __syncthreads();
    for (int it = 0; it < 32; ++it) {
        for (int i = t; i < 2048; i += 1024) Bn[i] = min(A_[i], A_[Y_[i]]);
        __syncthreads();
        for (int i = t; i < 2048; i += 1024) atomicMin(&Bn[Y_[i]], A_[i]);
        __syncthreads();
        int ch = 0;
        for (int i = t; i < 2048; i += 1024) {
            const int b = Bn[i];
            const int nv = min(b, Bn[b]);
            if (nv != A_[i]) { ch = 1; A_[i] = nv; }
        }
        if (ch) atomicOr(&chg, 1);
        __syncthreads();
        const int c = chg;
        __syncthreads();
        if (t == 0) chg = 0;
        if (!c) break;
    }
    for (int i = t; i < 2048; i += 1024) labg[br * 2048 + i] = A_[i];
}

// ---------------------------------------------------------------- per-row term from bf16 sim + exact LSE partials
__global__ __launch_bounds__(256) void loss_rows(const bf16_t* __restrict__ simb, const int* __restrict__ labels,
                                                 const float* __restrict__ lseP, float* __restrict__ terms)
{
    const int row = blockIdx.x;
    const int br  = row >> 11;
    const int* lab = labels + ((1 - br) << 11);
    const int self = row & 2047;
    const int li = lab[self];
    const int t = threadIdx.x;
    const bf16x8 v8 = *(const bf16x8*)(simb + (size_t)row * 2048 + t * 8);
    float psum = 0.f; int pc = 0;
#pragma unroll
    for (int j = 0; j < 8; ++j) {
        const int c = t * 8 + j;
        if (c == self) continue;
        if (lab[c] == li) { psum += 10.0f * (float)v8[j]; pc++; }
    }
    __shared__ float PS[256]; __shared__ int PC[256];
    PS[t] = psum; PC[t] = pc;
    __syncthreads();
    for (int off = 128; off; off >>= 1) {
        if (t < off) { PS[t] += PS[t + off]; PC[t] += PC[t + off]; }
        __syncthreads();
    }
    if (t == 0) {
        float se = 0.f;
        for (int nb = 0; nb < 16; ++nb) se += lseP[(size_t)nb * 4096 + row];
        terms[row] = logf(se) - PS[0] / (float)PC[0];
    }
}

// ---------------------------------------------------------------- final deterministic reduce
__global__ __launch_bounds__(1024) void final_reduce(const float* __restrict__ terms, float* __restrict__ out)
{
    const int t = threadIdx.x;
    float s = terms[t] + terms[t + 1024] + terms[t + 2048] + terms[t + 3072];
    __shared__ float S[1024];
    S[t] = s;
    __syncthreads();
    for (int off = 512; off; off >>= 1) { if (t < off) S[t] += S[t + off]; __syncthreads(); }
    if (t == 0) out[0] = S[0] * (1.0f / 4096.0f);
}

// ---------------------------------------------------------------- launch
extern "C" void kernel_launch(void* const* d_in, const int* in_sizes, int n_in,
                              void* d_out, int out_size, void* d_ws, size_t ws_size,
                              hipStream_t stream)
{
    const float* x1    = (const float*)d_in[0];
    const float* x2    = (const float*)d_in[1];
    const float* W1    = (const float*)d_in[2];
    const float* b1    = (const float*)d_in[3];
    const float* gamma = (const float*)d_in[4];
    const float* beta  = (const float*)d_in[5];
    const float* W2    = (const float*)d_in[6];
    const float* b2    = (const float*)d_in[7];

    char* ws = (char*)d_ws;
    const size_t MB = 1024ull * 1024ull;
    const size_t NN = 2048ull * 2048ull;
    bf16_t* W1b    = (bf16_t*)(ws + 0);
    bf16_t* W2b    = (bf16_t*)(ws + 8 * MB);
    bf16_t* xcatb  = (bf16_t*)(ws + 16 * MB);
    bf16_t* hnb    = (bf16_t*)(ws + 16 * MB);
    bf16_t* hb16   = (bf16_t*)(ws + 32 * MB);
    bf16_t* ob16   = (bf16_t*)(ws + 64 * MB);
    bf16_t* simb   = (bf16_t*)(ws + 0);
    float*  psA    = (float*)(ws + 80 * MB);               // [16][2048] col sums
    float*  psB    = psA + 32 * 2048;                       // [16][2048] col sumsq
    float*  rsq    = psB + 32 * 2048;                       // [16][4096] row sumsq
    float*  mu     = rsq + 16 * 4096;                       // [2][2048]
    float*  rinv   = mu + 4096;
    float*  rn     = rinv + 4096;                           // [4096]
    float*  lseP   = rn + 4096;                             // [16][4096]
    unsigned long long* pkey = (unsigned long long*)(lseP + 16 * 4096);  // [16][4096]
    int*    labels = (int*)(pkey + 16 * 4096);
    float*  terms  = (float*)(labels + 4096);

    // fused casts
    cast_all<<<16384, 256, 0, stream>>>(x1, x2, W1, W2, xcatb, W1b, W2b);

    // h = xcat @ W1^T + b1 -> bf16, fused BN-stat partials
    gemm8f<<<dim3(16, 16), 512, 0, stream>>>(xcatb, W1b, b1, hb16, 0, 1,
                                             psA, psB, nullptr, nullptr, nullptr, nullptr);
    bn_final2<<<16, 256, 0, stream>>>(psA, psB, mu, rinv);
    bn_apply<<<4096, 256, 0, stream>>>(hb16, mu, rinv, gamma, beta, hnb);

    // o = hn @ W2^T + b2 -> bf16, fused row-sumsq partials
    gemm8f<<<dim3(16, 16), 512, 0, stream>>>(hnb, W2b, b2, ob16, 0, 3,
                                             nullptr, nullptr, rsq, nullptr, nullptr, nullptr);
    norm_final<<<16, 256, 0, stream>>>(rsq, rn);

    // sim = [o1@o1^T ; o2@o2^T] * rn_m*rn_n -> bf16, fused row-argmax + row-LSE partials
    gemm8f<<<dim3(16, 16), 512, 0, stream>>>(ob16, ob16, nullptr, simb, (long long)NN, 2,
                                             nullptr, nullptr, nullptr, rn, pkey, lseP);

    // CC (argmax folded, early-exit) -> loss
    cc_labels<<<2, 1024, 0, stream>>>(pkey, labels);
    loss_rows<<<4096, 256, 0, stream>>>(simb, labels, lseP, terms);
    final_reduce<<<1, 1024, 0, stream>>>(terms, (float*)d_out);
}